// Round 5
// baseline (416.134 us; speedup 1.0000x reference)
//
#include <hip/hip_runtime.h>

#define NN 256
#define CC 64
#define TT 64
#define VV 25
#define SS 3
#define RR 8
#define OO 64
#define HH 16

typedef _Float16 f16;
typedef _Float16 f16x8 __attribute__((ext_vector_type(8)));
typedef float f32x4 __attribute__((ext_vector_type(4)));

#define IBN 0.9999950000374997f   /* 1/sqrt(1+1e-5) */

__device__ __forceinline__ float tanh_fast(float xx) {
  // tanh(x) = 1 - 2/(exp(2x)+1); exact at +-inf, ~1e-6 rel error
  float e = __expf(2.0f * xx);
  return 1.0f - __fdividef(2.0f, e + 1.0f);
}

// ---------------------------------------------------------------------------
// Fully-fused kernel: ONE block per n (grid 256, 512 threads, ~160KB LDS).
// No workspace at all: m never goes to HBM (rebuilt per (ob,s) in LDS from
// the cached att table; 80k FMA per build ~ trivial vs the 167MB of m
// traffic + 80MB workspace it replaces).
// Phases:
//  A: xm = mean_t x (contiguous chunks), x1/x2, SE gate (analytic, BN
//     folded), att[s][uv][r] = tanh_fast(x1-x2) cached f16 for all 3 s.
//  B: for tt(4): stage xsT; for ob(4): for s(3):
//       m-pass: mt[16o][25u][40v] = softmax_u(att.w4*alpha + Asym)  (LDS)
//       stage1: Z = W3*X + b3      (A-frags direct from f32 w3, L1-hot)
//       stage2: Y[t][u] += Z[t][v]*m[u][v]
//     epilogue: out = relu(Y*ibn*bn_w*se + bn_b*se + x)
// ---------------------------------------------------------------------------
struct __align__(16) SmemF {
  union { f16 xsT[400][72]; float part[64][8][25]; } u1;  // 57,600 B
  f16 zs[16][16][40];                                     // 20,480 B
  f16 mt[16][25][40];                                     // 32,000 B
  union { f16 att2h[15000]; float w12[3072]; } u2;        // 30,000 B
  float asym[1875];                                       //  7,500 B
  float xms[1600];                                        //  6,400 B
  float x1s[600];                                         //  2,400 B
  float x2s[600];                                         //  2,400 B
  float b3s[192];                                         //    768 B
  float sev[64];                                          //    256 B
  float pooledv[64];                                      //    256 B
  float hbuf[16];                                         //     64 B
  float xmv[64];                                          //    256 B
};                                                        // 160,380 B

__global__ __launch_bounds__(512) void kf(
    const float* __restrict__ x, const float* __restrict__ PA,
    const float* __restrict__ alpha,
    const float* __restrict__ w1, const float* __restrict__ b1,
    const float* __restrict__ w2, const float* __restrict__ b2,
    const float* __restrict__ w3, const float* __restrict__ b3,
    const float* __restrict__ w4, const float* __restrict__ b4,
    const float* __restrict__ bn_w, const float* __restrict__ bn_b,
    const float* __restrict__ se_w1, const float* __restrict__ se_b1,
    const float* __restrict__ se_w2, const float* __restrict__ se_b2,
    float* __restrict__ out)
{
  __shared__ SmemF sm;
  int n = blockIdx.x, tid = threadIdx.x;
  int lane = tid & 63, w = tid >> 6, q = lane >> 4, l15 = lane & 15;

  // ---- small loads + pad zeroing
  for (int i = tid; i < 1536; i += 512) {
    sm.u2.w12[i] = w1[i]; sm.u2.w12[1536 + i] = w2[i];
  }
  for (int i = tid; i < 1875; i += 512) {
    int s = i / 625, rem = i - s*625, u = rem / 25, v = rem - u*25;
    sm.asym[i] = PA[s*625 + u*25 + v] + PA[s*625 + v*25 + u];
  }
  if (tid < 192) sm.b3s[tid] = b3[tid];
  for (int i = tid; i < 3840; i += 512) {   // zs cols v=25..39 := 0 (K-pad)
    int op = i / 240, rem = i - op*240, t = rem / 15, v = 25 + (rem - t*15);
    sm.zs[op][t][v] = (f16)0.f;
  }
  for (int i = tid; i < 2800; i += 512) {   // mt cols v=25..31 := 0 (K-pad)
    int o = i / 175, rem = i - o*175, u = rem / 7, v = 25 + (rem - u*7);
    sm.mt[o][u][v] = (f16)0.f;
  }

  // ---- xm: contiguous 200-float chunk per thread
  {
    int c = tid >> 3, tq = tid & 7;
    const float* p = x + (size_t)(n*64 + c)*1600 + tq*200;   // 16B aligned
    float acc[25];
    #pragma unroll
    for (int i = 0; i < 25; ++i) acc[i] = 0.f;
    for (int blk = 0; blk < 2; ++blk) {      // 100 floats per blk, 100%25==0
      const float* pb = p + blk*100;
      #pragma unroll
      for (int j = 0; j < 25; ++j) {
        f32x4 vv = *(const f32x4*)(pb + 4*j);
        acc[(4*j + 0) % 25] += vv[0];
        acc[(4*j + 1) % 25] += vv[1];
        acc[(4*j + 2) % 25] += vv[2];
        acc[(4*j + 3) % 25] += vv[3];
      }
    }
    #pragma unroll
    for (int i = 0; i < 25; ++i) sm.u1.part[c][tq][i] = acc[i];
  }
  __syncthreads();

  for (int idx = tid; idx < 1600; idx += 512) {
    int cc = idx / 25, v = idx - cc*25;
    float s = 0.f;
    #pragma unroll
    for (int tq = 0; tq < 8; ++tq) s += sm.u1.part[cc][tq][v];
    sm.xms[idx] = s * (1.0f/64.0f);
  }
  __syncthreads();

  // ---- x1/x2 + xmv (reads xms, w12)
  for (int idx = tid; idx < 600; idx += 512) {
    int sr = idx / 25, v = idx - sr*25;
    float a1 = b1[sr], a2 = b2[sr];
    #pragma unroll
    for (int c = 0; c < 64; ++c) {
      float xv = sm.xms[c*25 + v];
      a1 += xv * sm.u2.w12[sr*64 + c];
      a2 += xv * sm.u2.w12[1536 + sr*64 + c];
    }
    sm.x1s[idx] = a1; sm.x2s[idx] = a2;
  }
  if (tid < 64) {
    float s = 0.f;
    #pragma unroll
    for (int v = 0; v < 25; ++v) s += sm.xms[tid*25 + v];
    sm.xmv[tid] = s * (1.0f/25.0f);
  }
  __syncthreads();

  // ---- att table (all 3 s, f16, overlays dead w12) + SE pooled
  for (int idx = tid; idx < 15000; idx += 512) {
    int sA = idx / 5000, rem = idx - sA*5000;
    int uv = rem >> 3, r = rem & 7;
    int u = uv / 25, v = uv - u*25;
    sm.u2.att2h[idx] =
        (f16)tanh_fast(sm.x1s[(sA*8 + r)*25 + u] - sm.x2s[(sA*8 + r)*25 + v]);
  }
  if (tid < 64) {
    int o = tid;
    float pp = b3[o] + b3[64 + o] + b3[128 + o];
    for (int cc = 0; cc < 64; ++cc)
      pp += sm.xmv[cc] * (w3[o*64 + cc] + w3[4096 + o*64 + cc] + w3[8192 + o*64 + cc]);
    sm.pooledv[o] = IBN * bn_w[o] * pp + bn_b[o];
  }
  __syncthreads();
  if (tid < 16) {
    float hh = se_b1[tid];
    for (int o = 0; o < 64; ++o) hh += sm.pooledv[o] * se_w1[tid*64 + o];
    sm.hbuf[tid] = fmaxf(hh, 0.0f);
  }
  __syncthreads();
  if (tid < 64) {
    float t = se_b2[tid];
    for (int j = 0; j < 16; ++j) t += sm.hbuf[j] * se_w2[tid*16 + j];
    sm.sev[tid] = 1.0f / (1.0f + __expf(-t));
  }
  // sev published by the tloc-top barrier below

  // ---- main loop over t-tiles
  const size_t xbase = (size_t)n*64*1600;
  for (int tloc = 0; tloc < 4; ++tloc) {
    __syncthreads();   // xsT free (prev stage1/epilogue reads done; part dead)

    // stage X tile: [cb:8][j:400] units -> b128 LDS writes (conflict-free)
    {
      const float* xb = x + xbase + tloc*400;
      for (int idx = tid; idx < 3200; idx += 512) {
        int cb = idx / 400, j = idx - cb*400;
        f16x8 hv;
        #pragma unroll
        for (int k = 0; k < 8; ++k) hv[k] = (f16)xb[(cb*8 + k)*1600 + j];
        *(f16x8*)&sm.u1.xsT[j][cb*8] = hv;
      }
    }
    __syncthreads();

    for (int ob = 0; ob < 4; ++ob) {
      f32x4 yacc[2][2];
      #pragma unroll
      for (int i = 0; i < 2; ++i) {
        yacc[i][0] = (f32x4){0.f,0.f,0.f,0.f};
        yacc[i][1] = (f32x4){0.f,0.f,0.f,0.f};
      }

      for (int s = 0; s < 3; ++s) {
        __syncthreads();   // prev stage2 done reading zs/mt

        // A-frags direct from f32 w3 (48KB table, L1/L2-hot); issue early
        const float* wr = w3 + ((s*64 + ob*16 + l15) << 6) + q*8;
        f32x4 wa = *(const f32x4*)(wr);
        f32x4 wb = *(const f32x4*)(wr + 4);
        f32x4 wc = *(const f32x4*)(wr + 32);
        f32x4 wd = *(const f32x4*)(wr + 36);
        f16x8 a0, a1;
        #pragma unroll
        for (int k = 0; k < 4; ++k) {
          a0[k] = (f16)wa[k]; a0[4 + k] = (f16)wb[k];
          a1[k] = (f16)wc[k]; a1[4 + k] = (f16)wd[k];
        }

        // ---- m-pass: mt[16][25][40] = softmax_u(att.w4*alpha + Asym)
        if (tid < 400) {
          int ot = tid / 25, v = tid - ot*25;
          int og = s*64 + ob*16 + ot;
          float alphav = alpha[s];
          float b4r = b4[og];
          float w4r[8];
          #pragma unroll
          for (int r = 0; r < 8; ++r) w4r[r] = w4[og*8 + r];
          float acc[25];
          #pragma unroll
          for (int u = 0; u < 25; ++u) {
            f16x8 av = *(const f16x8*)&sm.u2.att2h[s*5000 + (u*25 + v)*8];
            float t = b4r;
            #pragma unroll
            for (int r = 0; r < 8; ++r) t += (float)av[r] * w4r[r];
            acc[u] = t*alphav + sm.asym[s*625 + u*25 + v];
          }
          float mx = -1e30f;
          #pragma unroll
          for (int u = 0; u < 25; ++u) mx = fmaxf(mx, acc[u]);
          float sum = 0.f;
          #pragma unroll
          for (int u = 0; u < 25; ++u) {
            float e = __expf(acc[u] - mx); acc[u] = e; sum += e;
          }
          float inv = 1.0f / sum;
          #pragma unroll
          for (int u = 0; u < 25; ++u) sm.mt[ot][u][v] = (f16)(acc[u]*inv);
        }

        // ---- stage1: Z = W3*X + b3 -> zs (8 waves stride rows)
        for (int ni = w; ni < 25; ni += 8) {
          int row = ni*16 + l15;                   // j = t*25+v (D n-col)
          f16x8 bf0 = *(const f16x8*)&sm.u1.xsT[row][q*8];
          f16x8 bf1 = *(const f16x8*)&sm.u1.xsT[row][32 + q*8];
          f32x4 acc = (f32x4){0.f,0.f,0.f,0.f};
          acc = __builtin_amdgcn_mfma_f32_16x16x32_f16(a0, bf0, acc, 0, 0, 0);
          acc = __builtin_amdgcn_mfma_f32_16x16x32_f16(a1, bf1, acc, 0, 0, 0);
          int t = row / 25, v = row - t*25;
          #pragma unroll
          for (int rg = 0; rg < 4; ++rg) {
            int op = q*4 + rg;                     // D m-row = o'
            sm.zs[op][t][v] = (f16)(acc[rg] + sm.b3s[s*64 + ob*16 + op]);
          }
        }
        __syncthreads();   // mt + zs ready

        // ---- stage2: Y[t][u] += Z[t][v] * m[u][v]
        int uc = 16 + l15; if (uc > 24) uc = 24;   // clamp, cols discarded
        #pragma unroll
        for (int i = 0; i < 2; ++i) {
          int op = w*2 + i;
          f16x8 az  = *(const f16x8*)&sm.zs[op][l15][q*8];   // A[t][v]
          f16x8 bm0 = *(const f16x8*)&sm.mt[op][l15][q*8];   // B[v][u]=m[u][v]
          f16x8 bm1 = *(const f16x8*)&sm.mt[op][uc][q*8];
          yacc[i][0] = __builtin_amdgcn_mfma_f32_16x16x32_f16(az, bm0, yacc[i][0], 0, 0, 0);
          yacc[i][1] = __builtin_amdgcn_mfma_f32_16x16x32_f16(az, bm1, yacc[i][1], 0, 0, 0);
        }
      }

      // ---- epilogue for this o-block: BN+SE+residual+ReLU
      #pragma unroll
      for (int i = 0; i < 2; ++i) {
        int op = w*2 + i, o = ob*16 + op;
        float se    = sm.sev[o];
        float scale = IBN * bn_w[o] * se;
        float bias  = bn_b[o] * se;
        #pragma unroll
        for (int ut = 0; ut < 2; ++ut) {
          int u = ut*16 + l15;
          if (u < 25) {
            #pragma unroll
            for (int rg = 0; rg < 4; ++rg) {
              int t = q*4 + rg;                               // D m-row = t
              float xres = (float)sm.u1.xsT[t*25 + u][o];
              float val = yacc[i][ut][rg]*scale + bias + xres;
              out[(((size_t)n*64 + o)*64 + tloc*16 + t)*25 + u] = fmaxf(val, 0.0f);
            }
          }
        }
      }
    }
  }
}

// ---------------------------------------------------------------------------
extern "C" void kernel_launch(void* const* d_in, const int* in_sizes, int n_in,
                              void* d_out, int out_size, void* d_ws, size_t ws_size,
                              hipStream_t stream)
{
  const float* x    = (const float*)d_in[0];
  const float* PA   = (const float*)d_in[1];
  const float* alp  = (const float*)d_in[2];
  const float* w1   = (const float*)d_in[3];
  const float* b1   = (const float*)d_in[4];
  const float* w2   = (const float*)d_in[5];
  const float* b2   = (const float*)d_in[6];
  const float* w3   = (const float*)d_in[7];
  const float* b3   = (const float*)d_in[8];
  const float* w4   = (const float*)d_in[9];
  const float* b4   = (const float*)d_in[10];
  const float* bnw  = (const float*)d_in[11];
  const float* bnb  = (const float*)d_in[12];
  const float* sw1  = (const float*)d_in[13];
  const float* sb1  = (const float*)d_in[14];
  const float* sw2  = (const float*)d_in[15];
  const float* sb2  = (const float*)d_in[16];

  float* out = (float*)d_out;

  // Zero workspace use: m is rebuilt in LDS per (ob,s); SE stays in LDS.
  kf<<<256, 512, 0, stream>>>(x, PA, alp, w1, b1, w2, b2, w3, b3, w4, b4,
                              bnw, bnb, sw1, sb1, sw2, sb2, out);
}